// Round 7
// baseline (103.983 us; speedup 1.0000x reference)
//
#include <hip/hip_runtime.h>
#include <hip/hip_bf16.h>

#define N_TOTAL 4096
#define C_DIM 256
#define K_NEG 128
#define HW 1024
#define TEMP_INV (1.0f / 0.07f)

typedef _Float16 h8 __attribute__((ext_vector_type(8)));
typedef _Float16 h2 __attribute__((ext_vector_type(2)));

// async global->LDS, 16B per lane; LDS dest is wave-uniform base + lane*16.
__device__ __forceinline__ void lds_dma16(const void* g, void* l) {
  __builtin_amdgcn_global_load_lds(
      (const __attribute__((address_space(1))) void*)g,
      (__attribute__((address_space(3))) void*)l, 16, 0, 0);
}

// ---------------------------------------------------------------------------
// Kernel 1 (fused): transpose [B,C,HW] -> [N,C] RAW f16 + per-row sumsq
// partials (atomicAdd into ss[2][4096]). Normalization deferred to nce.
// 512 blocks = 2 tensors x 64 spatial chunks x 4 channel quarters.
// ---------------------------------------------------------------------------
__global__ __launch_bounds__(256) void tr_ss_kernel(
    const float* __restrict__ fq, const float* __restrict__ fk,
    _Float16* __restrict__ qh, _Float16* __restrict__ kh,
    float* __restrict__ ss) {
  const int bid = blockIdx.x;
  const int tensor = bid >> 8;        // 0=q, 1=k
  const int sp = (bid >> 2) & 63;     // spatial chunk (64 rows)
  const int cc = bid & 3;             // channel quarter (64 channels)
  const float* in = tensor ? fk : fq;
  _Float16* out = tensor ? kh : qh;
  const int n0 = sp * 64;
  const int b = n0 / HW, s0 = n0 % HW;
  const float* base = in + (size_t)b * C_DIM * HW + s0;

  const int t = threadIdx.x, lane = t & 63, w = t >> 6;
  __shared__ float tile[64][65];
  __shared__ float red[4][64];

  // ---- load 64ch x 64sp tile, float4 along spatial ----
  const int chl = t >> 4;             // 0..15
  const int sp4 = (t & 15) * 4;
#pragma unroll
  for (int p = 0; p < 4; ++p) {
    int cl = p * 16 + chl;
    const float4 v =
        *(const float4*)(base + (size_t)(cc * 64 + cl) * HW + sp4);
    tile[cl][sp4] = v.x; tile[cl][sp4 + 1] = v.y;
    tile[cl][sp4 + 2] = v.z; tile[cl][sp4 + 3] = v.w;
  }
  __syncthreads();

  // ---- per-row partial sum of squares over this channel quarter ----
  float acc = 0.f;
#pragma unroll
  for (int j = 0; j < 16; ++j) {
    float v = tile[w * 16 + j][lane];
    acc = fmaf(v, v, acc);
  }
  red[w][lane] = acc;
  __syncthreads();
  if (w == 0) {
    float tot = red[0][lane] + red[1][lane] + red[2][lane] + red[3][lane];
    atomicAdd(&ss[tensor * N_TOTAL + n0 + lane], tot);
  }

  // ---- transposed raw-f16 write: 32B contiguous per thread ----
  const int wsp = t >> 2, q4 = t & 3;
  h8 o0, o1;
#pragma unroll
  for (int j = 0; j < 8; ++j) o0[j] = (_Float16)tile[q4 * 16 + j][wsp];
#pragma unroll
  for (int j = 0; j < 8; ++j) o1[j] = (_Float16)tile[q4 * 16 + 8 + j][wsp];
  h8* dst = (h8*)(out + (size_t)(n0 + wsp) * C_DIM + cc * 64 + q4 * 16);
  dst[0] = o0;
  dst[1] = o1;
}

// ---------------------------------------------------------------------------
// Kernel 2: per-row InfoNCE via LDS-DMA gather. One block per row.
// Phase 1: each wave DMAs its 32 negative rows (16 x 1KB global_load_lds,
//   2 rows/instr) into krows[128][256] -- ~64KB queued per block, no VGPR
//   cost, saturating the L2 gather (reg-staging could not: Little's law).
// Phase 2: unit u of wave w dots rows w*32+u*4..+3 from LDS (linear layout
//   is bank-uniform: for fixed chunk i the 64 lanes tile all 32 banks x8).
// ---------------------------------------------------------------------------
__global__ __launch_bounds__(256) void nce_kernel(
    const _Float16* __restrict__ qh, const _Float16* __restrict__ kh,
    const float* __restrict__ ss, const int* __restrict__ neg,
    float* __restrict__ loss_buf) {
  const int n = blockIdx.x;
  const int t = threadIdx.x;
  const int lane = t & 63;
  const int w = t >> 6;
  const int sub = lane & 7;            // lane within 8-lane dot unit
  const int unit = lane >> 3;          // 0..7

  __shared__ __align__(16) _Float16 krows[K_NEG][C_DIM];  // 64 KiB
  __shared__ float sinvk[K_NEG];
  __shared__ float sneg[K_NEG];
  __shared__ float s_lpos;

  const float* ssk_arr = ss + N_TOTAL;

  // ---- q row chunks: lane sub owns h8 chunks {sub, 8+sub, 16+sub, 24+sub}
  const h8* qrow = (const h8*)(qh + (size_t)n * C_DIM);
  h8 qv[4];
#pragma unroll
  for (int i = 0; i < 4; ++i) qv[i] = qrow[i * 8 + sub];
  float ssq = ss[n];

  // ---- positive row into regs (lanes 0-7 only; L2-hot) ----
  h8 kp[4];
  float sskp = 1.f;
  if (t < 8) {
    const h8* kr = (const h8*)(kh + (size_t)n * C_DIM);
#pragma unroll
    for (int i = 0; i < 4; ++i) kp[i] = kr[i * 8 + sub];
    sskp = ssk_arr[n];
  }

  // ---- per-wave: lanes 0-31 load + fix 32 indices, stash inv-norms ----
  int myidx = 0;
  if (lane < 32) {
    int x = neg[(size_t)n * K_NEG + w * 32 + lane];
    myidx = x + (x >= n ? 1 : 0);      // self-exclusion shift
    sinvk[w * 32 + lane] = 1.0f / fmaxf(sqrtf(ssk_arr[myidx]), 1e-12f);
  }

  // ---- DMA this wave's 32 rows: instr j covers local rows 2j, 2j+1 ----
#pragma unroll
  for (int j = 0; j < 16; ++j) {
    int r0 = __shfl(myidx, 2 * j + (lane >> 5));   // per-lane source row
    const char* src =
        (const char*)(kh + (size_t)r0 * C_DIM) + (lane & 31) * 16;
    lds_dma16(src, &krows[w * 32 + 2 * j][0]);
  }
  asm volatile("s_waitcnt vmcnt(0) lgkmcnt(0)" ::: "memory");
  __syncthreads();

  const float invq = 1.0f / fmaxf(sqrtf(ssq), 1e-12f);
  union H { h8 v; h2 p[4]; };

  // ---- 4 rows per unit from LDS ----
#pragma unroll
  for (int jj = 0; jj < 4; ++jj) {
    const int rr = w * 32 + unit * 4 + jj;
    const h8* kr = (const h8*)&krows[rr][0];
    float a0 = 0.f, a1 = 0.f;
#pragma unroll
    for (int i = 0; i < 4; ++i) {
      H a; a.v = qv[i];
      H b; b.v = kr[i * 8 + sub];      // ds_read_b128, bank-uniform
      a0 = __builtin_amdgcn_fdot2(b.p[0], a.p[0], a0, false);
      a1 = __builtin_amdgcn_fdot2(b.p[1], a.p[1], a1, false);
      a0 = __builtin_amdgcn_fdot2(b.p[2], a.p[2], a0, false);
      a1 = __builtin_amdgcn_fdot2(b.p[3], a.p[3], a1, false);
    }
    float acc = a0 + a1;
    acc += __shfl_xor(acc, 1);
    acc += __shfl_xor(acc, 2);
    acc += __shfl_xor(acc, 4);
    if (sub == 0) sneg[rr] = acc * invq * sinvk[rr];
  }

  // ---- positive dot (lanes 0-7) ----
  if (t < 8) {
    float a0 = 0.f, a1 = 0.f;
#pragma unroll
    for (int i = 0; i < 4; ++i) {
      H a; a.v = qv[i];
      H b; b.v = kp[i];
      a0 = __builtin_amdgcn_fdot2(b.p[0], a.p[0], a0, false);
      a1 = __builtin_amdgcn_fdot2(b.p[1], a.p[1], a1, false);
      a0 = __builtin_amdgcn_fdot2(b.p[2], a.p[2], a0, false);
      a1 = __builtin_amdgcn_fdot2(b.p[3], a.p[3], a1, false);
    }
    float acc = a0 + a1;
    acc += __shfl_xor(acc, 1);
    acc += __shfl_xor(acc, 2);
    acc += __shfl_xor(acc, 4);
    if (t == 0) s_lpos = acc * invq * (1.0f / fmaxf(sqrtf(sskp), 1e-12f));
  }
  __syncthreads();

  // ---- wave 0: logsumexp over 129 logits; plain store ----
  if (w == 0) {
    float lp = s_lpos * TEMP_INV;
    float x1 = sneg[lane] * TEMP_INV;
    float x2 = sneg[lane + 64] * TEMP_INV;
    float m = fmaxf(fmaxf(x1, x2), lp);
#pragma unroll
    for (int off = 32; off; off >>= 1) m = fmaxf(m, __shfl_xor(m, off));
    float s = __expf(x1 - m) + __expf(x2 - m);
#pragma unroll
    for (int off = 32; off; off >>= 1) s += __shfl_xor(s, off);
    if (lane == 0) loss_buf[n] = m + __logf(s) - lp;
  }
}

// ---------------------------------------------------------------------------
// Kernel 3: mean over 4096 per-row losses. One block, 1024 threads.
// ---------------------------------------------------------------------------
__global__ __launch_bounds__(1024) void reduce_kernel(
    const float* __restrict__ loss_buf, float* __restrict__ out) {
  const int t = threadIdx.x;
  const float4 v = ((const float4*)loss_buf)[t];
  float s = (v.x + v.y) + (v.z + v.w);
#pragma unroll
  for (int off = 32; off; off >>= 1) s += __shfl_xor(s, off);
  __shared__ float red[16];
  if ((t & 63) == 0) red[t >> 6] = s;
  __syncthreads();
  if (t < 16) {
    float x = red[t];
#pragma unroll
    for (int off = 8; off; off >>= 1) x += __shfl_xor(x, off);
    if (t == 0) out[0] = x * (1.0f / N_TOTAL);
  }
}

extern "C" void kernel_launch(void* const* d_in, const int* in_sizes, int n_in,
                              void* d_out, int out_size, void* d_ws,
                              size_t ws_size, hipStream_t stream) {
  const float* fq = (const float*)d_in[0];
  const float* fk = (const float*)d_in[1];
  const int* neg = (const int*)d_in[2];
  float* out = (float*)d_out;

  _Float16* qh = (_Float16*)d_ws;                        // 2 MiB
  _Float16* kh = qh + (size_t)N_TOTAL * C_DIM;           // 2 MiB
  float* ss = (float*)(kh + (size_t)N_TOTAL * C_DIM);    // 32 KiB
  float* loss_buf = ss + 2 * N_TOTAL;                    // 16 KiB

  hipMemsetAsync(ss, 0, 2 * N_TOTAL * sizeof(float), stream);
  hipLaunchKernelGGL(tr_ss_kernel, dim3(512), dim3(256), 0, stream,
                     fq, fk, qh, kh, ss);
  hipLaunchKernelGGL(nce_kernel, dim3(N_TOTAL), dim3(256), 0, stream,
                     qh, kh, ss, neg, loss_buf);
  hipLaunchKernelGGL(reduce_kernel, dim3(1), dim3(1024), 0, stream,
                     loss_buf, out);
}

// Round 8
// 88.308 us; speedup vs baseline: 1.1775x; 1.1775x over previous
//
#include <hip/hip_runtime.h>
#include <hip/hip_bf16.h>

#define N_TOTAL 4096
#define C_DIM 256
#define K_NEG 128
#define HW 1024
#define TEMP_INV (1.0f / 0.07f)

typedef _Float16 h8 __attribute__((ext_vector_type(8)));
typedef _Float16 h2 __attribute__((ext_vector_type(2)));

// ---------------------------------------------------------------------------
// Kernel 1 (fused): transpose [B,C,HW] -> [N,C] RAW f16 + per-row sumsq
// PARTIALS (plain store into ssp[2][4][N]; no atomics, no memset).
// Normalization deferred to nce. 512 blocks = 2 tensors x 64 sp x 4 cc.
// ---------------------------------------------------------------------------
__global__ __launch_bounds__(256) void tr_ss_kernel(
    const float* __restrict__ fq, const float* __restrict__ fk,
    _Float16* __restrict__ qh, _Float16* __restrict__ kh,
    float* __restrict__ ssp) {
  const int bid = blockIdx.x;
  const int tensor = bid >> 8;        // 0=q, 1=k
  const int sp = (bid >> 2) & 63;     // spatial chunk (64 rows)
  const int cc = bid & 3;             // channel quarter (64 channels)
  const float* in = tensor ? fk : fq;
  _Float16* out = tensor ? kh : qh;
  const int n0 = sp * 64;
  const int b = n0 / HW, s0 = n0 % HW;
  const float* base = in + (size_t)b * C_DIM * HW + s0;

  const int t = threadIdx.x, lane = t & 63, w = t >> 6;
  __shared__ float tile[64][65];
  __shared__ float red[4][64];

  // ---- load 64ch x 64sp tile, float4 along spatial ----
  const int chl = t >> 4;             // 0..15
  const int sp4 = (t & 15) * 4;
#pragma unroll
  for (int p = 0; p < 4; ++p) {
    int cl = p * 16 + chl;
    const float4 v =
        *(const float4*)(base + (size_t)(cc * 64 + cl) * HW + sp4);
    tile[cl][sp4] = v.x; tile[cl][sp4 + 1] = v.y;
    tile[cl][sp4 + 2] = v.z; tile[cl][sp4 + 3] = v.w;
  }
  __syncthreads();

  // ---- per-row partial sum of squares over this channel quarter ----
  float acc = 0.f;
#pragma unroll
  for (int j = 0; j < 16; ++j) {
    float v = tile[w * 16 + j][lane];
    acc = fmaf(v, v, acc);
  }
  red[w][lane] = acc;
  __syncthreads();
  if (w == 0) {
    float tot = red[0][lane] + red[1][lane] + red[2][lane] + red[3][lane];
    ssp[((size_t)tensor * 4 + cc) * N_TOTAL + n0 + lane] = tot;
  }

  // ---- transposed raw-f16 write: 32B contiguous per thread ----
  const int wsp = t >> 2, q4 = t & 3;
  h8 o0, o1;
#pragma unroll
  for (int j = 0; j < 8; ++j) o0[j] = (_Float16)tile[q4 * 16 + j][wsp];
#pragma unroll
  for (int j = 0; j < 8; ++j) o1[j] = (_Float16)tile[q4 * 16 + 8 + j][wsp];
  h8* dst = (h8*)(out + (size_t)(n0 + wsp) * C_DIM + cc * 64 + q4 * 16);
  dst[0] = o0;
  dst[1] = o1;
}

// ---------------------------------------------------------------------------
// Kernel 2: per-row InfoNCE. One block per row, 32 units of 8 lanes.
// The 16 gathered row-chunk loads are inline-asm global_load_dwordx4 with
// distinct "=&v" destinations: the compiler cannot interleave its own
// waitcnts or reuse the registers, so all 16 stay in flight (R5/R6's
// VGPR=68 proved C++ staging gets serialized). One vmcnt(0) drains them.
// Normal loads are fully drained BEFORE the asm region so compiler vmcnt
// bookkeeping never undercounts.
// ---------------------------------------------------------------------------
__global__ __launch_bounds__(256, 2) void nce_kernel(
    const _Float16* __restrict__ qh, const _Float16* __restrict__ kh,
    const float* __restrict__ ssp, const int* __restrict__ neg,
    float* __restrict__ loss_buf) {
  const int n = blockIdx.x;
  const int t = threadIdx.x;
  const int lane = t & 63;
  const int w = t >> 6;
  const int sub = lane & 7;              // lane within 8-lane dot unit
  const int unit = w * 8 + (lane >> 3);  // 0..31

  __shared__ float sneg[K_NEG];
  __shared__ float s_lpos;

  const float* ssq_p = ssp;               // [4][N]
  const float* ssk_p = ssp + 4 * N_TOTAL; // [4][N]

  // ===== phase A: all normal loads =====
  int r[4];
#pragma unroll
  for (int j = 0; j < 4; ++j) {
    int x = neg[(size_t)n * K_NEG + j * 32 + unit];
    r[j] = x + (x >= n ? 1 : 0);         // self-exclusion shift
  }
  const h8* qrow = (const h8*)(qh + (size_t)n * C_DIM);
  h8 qv[4];
#pragma unroll
  for (int i = 0; i < 4; ++i) qv[i] = qrow[i * 8 + sub];

  float ssq = ssq_p[n] + ssq_p[N_TOTAL + n] + ssq_p[2 * N_TOTAL + n] +
              ssq_p[3 * N_TOTAL + n];

  h8 kp[4];
  float sskp = 1.f;
  if (unit == 0) {
    const h8* kr = (const h8*)(kh + (size_t)n * C_DIM);
#pragma unroll
    for (int i = 0; i < 4; ++i) kp[i] = kr[i * 8 + sub];
    sskp = ssk_p[n] + ssk_p[N_TOTAL + n] + ssk_p[2 * N_TOTAL + n] +
           ssk_p[3 * N_TOTAL + n];
  }
  float ssk[4];
#pragma unroll
  for (int j = 0; j < 4; ++j)
    ssk[j] = ssk_p[r[j]] + ssk_p[N_TOTAL + r[j]] + ssk_p[2 * N_TOTAL + r[j]] +
             ssk_p[3 * N_TOTAL + r[j]];

  // drain all normal loads; nothing crosses this point
  asm volatile("s_waitcnt vmcnt(0) lgkmcnt(0)" ::: "memory");
  __builtin_amdgcn_sched_barrier(0);

  // ===== phase B: 16 asm gather loads, all in flight simultaneously =====
  float4 kd[4][4];
#pragma unroll
  for (int j = 0; j < 4; ++j) {
    const char* rbase = (const char*)(kh + (size_t)r[j] * C_DIM);
#pragma unroll
    for (int i = 0; i < 4; ++i) {
      const void* addr = rbase + (i * 8 + sub) * 16;
      asm volatile("global_load_dwordx4 %0, %1, off"
                   : "=&v"(kd[j][i])
                   : "v"(addr));
    }
  }
  asm volatile("s_waitcnt vmcnt(0)" ::: "memory");
  __builtin_amdgcn_sched_barrier(0);

  // ===== phase C: compute =====
  const float invq = 1.0f / fmaxf(sqrtf(ssq), 1e-12f);
  union H { float4 f; h8 v; h2 p[4]; };

#pragma unroll
  for (int j = 0; j < 4; ++j) {
    float a0 = 0.f, a1 = 0.f;
#pragma unroll
    for (int i = 0; i < 4; ++i) {
      H a; a.v = qv[i];
      H b; b.f = kd[j][i];
      a0 = __builtin_amdgcn_fdot2(b.p[0], a.p[0], a0, false);
      a1 = __builtin_amdgcn_fdot2(b.p[1], a.p[1], a1, false);
      a0 = __builtin_amdgcn_fdot2(b.p[2], a.p[2], a0, false);
      a1 = __builtin_amdgcn_fdot2(b.p[3], a.p[3], a1, false);
    }
    float acc = a0 + a1;
    acc += __shfl_xor(acc, 1);
    acc += __shfl_xor(acc, 2);
    acc += __shfl_xor(acc, 4);
    if (sub == 0) {
      float invk = 1.0f / fmaxf(sqrtf(ssk[j]), 1e-12f);
      sneg[j * 32 + unit] = acc * invq * invk;
    }
  }
  if (unit == 0) {
    float a0 = 0.f, a1 = 0.f;
#pragma unroll
    for (int i = 0; i < 4; ++i) {
      H a; a.v = qv[i];
      H b; b.v = kp[i];
      a0 = __builtin_amdgcn_fdot2(b.p[0], a.p[0], a0, false);
      a1 = __builtin_amdgcn_fdot2(b.p[1], a.p[1], a1, false);
      a0 = __builtin_amdgcn_fdot2(b.p[2], a.p[2], a0, false);
      a1 = __builtin_amdgcn_fdot2(b.p[3], a.p[3], a1, false);
    }
    float acc = a0 + a1;
    acc += __shfl_xor(acc, 1);
    acc += __shfl_xor(acc, 2);
    acc += __shfl_xor(acc, 4);
    if (sub == 0) {
      float invk = 1.0f / fmaxf(sqrtf(sskp), 1e-12f);
      s_lpos = acc * invq * invk;
    }
  }
  __syncthreads();

  // ===== wave 0: logsumexp over 129 logits; plain store =====
  if (w == 0) {
    float lp = s_lpos * TEMP_INV;
    float x1 = sneg[lane] * TEMP_INV;
    float x2 = sneg[lane + 64] * TEMP_INV;
    float m = fmaxf(fmaxf(x1, x2), lp);
#pragma unroll
    for (int off = 32; off; off >>= 1) m = fmaxf(m, __shfl_xor(m, off));
    float s = __expf(x1 - m) + __expf(x2 - m);
#pragma unroll
    for (int off = 32; off; off >>= 1) s += __shfl_xor(s, off);
    if (lane == 0) loss_buf[n] = m + __logf(s) - lp;
  }
}

// ---------------------------------------------------------------------------
// Kernel 3: mean over 4096 per-row losses. One block, 1024 threads.
// ---------------------------------------------------------------------------
__global__ __launch_bounds__(1024) void reduce_kernel(
    const float* __restrict__ loss_buf, float* __restrict__ out) {
  const int t = threadIdx.x;
  const float4 v = ((const float4*)loss_buf)[t];
  float s = (v.x + v.y) + (v.z + v.w);
#pragma unroll
  for (int off = 32; off; off >>= 1) s += __shfl_xor(s, off);
  __shared__ float red[16];
  if ((t & 63) == 0) red[t >> 6] = s;
  __syncthreads();
  if (t < 16) {
    float x = red[t];
#pragma unroll
    for (int off = 8; off; off >>= 1) x += __shfl_xor(x, off);
    if (t == 0) out[0] = x * (1.0f / N_TOTAL);
  }
}

extern "C" void kernel_launch(void* const* d_in, const int* in_sizes, int n_in,
                              void* d_out, int out_size, void* d_ws,
                              size_t ws_size, hipStream_t stream) {
  const float* fq = (const float*)d_in[0];
  const float* fk = (const float*)d_in[1];
  const int* neg = (const int*)d_in[2];
  float* out = (float*)d_out;

  _Float16* qh = (_Float16*)d_ws;                        // 2 MiB
  _Float16* kh = qh + (size_t)N_TOTAL * C_DIM;           // 2 MiB
  float* ssp = (float*)(kh + (size_t)N_TOTAL * C_DIM);   // 128 KiB [2][4][N]
  float* loss_buf = ssp + 8 * N_TOTAL;                   // 16 KiB

  hipLaunchKernelGGL(tr_ss_kernel, dim3(512), dim3(256), 0, stream,
                     fq, fk, qh, kh, ssp);
  hipLaunchKernelGGL(nce_kernel, dim3(N_TOTAL), dim3(256), 0, stream,
                     qh, kh, ssp, neg, loss_buf);
  hipLaunchKernelGGL(reduce_kernel, dim3(1), dim3(1024), 0, stream,
                     loss_buf, out);
}

// Round 9
// 82.415 us; speedup vs baseline: 1.2617x; 1.0715x over previous
//
#include <hip/hip_runtime.h>
#include <hip/hip_bf16.h>

#define N_TOTAL 4096
#define C_DIM 256
#define K_NEG 128
#define HW 1024
#define TEMP_INV (1.0f / 0.07f)

typedef _Float16 h8 __attribute__((ext_vector_type(8)));
typedef _Float16 h2 __attribute__((ext_vector_type(2)));

// ---------------------------------------------------------------------------
// Kernel 1: normalize + transpose, single pass. 512 blocks = 2 tensors x 256
// chunks of 16 full rows. Block loads 16 rows x 256 ch into LDS, computes
// each row's norm, writes NORMALIZED f16 rows (q rows also carry 1/T).
// => nce needs no norm loads at all (round-8 lesson: per-lane scalar norm
// gathers cost 64 cache lines per instruction, ~25us of line traffic).
// ---------------------------------------------------------------------------
__global__ __launch_bounds__(256) void norm_tr_kernel(
    const float* __restrict__ fq, const float* __restrict__ fk,
    _Float16* __restrict__ qh, _Float16* __restrict__ kh) {
  const int bid = blockIdx.x;
  const int tensor = bid >> 8;         // 0=q, 1=k
  const int chunk = bid & 255;         // 16-row chunk
  const int n0 = chunk * 16;
  const int b = n0 / HW, s0 = n0 % HW;
  const float* base = (tensor ? fk : fq) + (size_t)b * C_DIM * HW + s0;
  _Float16* out = tensor ? kh : qh;
  const float scale_extra = tensor ? 1.0f : TEMP_INV;  // fold 1/T into q

  const int t = threadIdx.x;
  __shared__ float tile[16][C_DIM + 1];   // [spatial][channel], 16.4 KB
  __shared__ float red[16][17];
  __shared__ float sinv[16];

  // ---- load: thread t = channel c; 16 spatial floats as 4x float4 ----
  {
    const int c = t;
    const float* src = base + (size_t)c * HW;
#pragma unroll
    for (int p = 0; p < 4; ++p) {
      const float4 v = *(const float4*)(src + p * 4);
      tile[p * 4 + 0][c] = v.x;
      tile[p * 4 + 1][c] = v.y;
      tile[p * 4 + 2][c] = v.z;
      tile[p * 4 + 3][c] = v.w;
    }
  }
  __syncthreads();

  // ---- sum of squares per row: 16 threads/row x 16 channels each ----
  {
    const int s = t & 15, cg = t >> 4;
    float acc = 0.f;
#pragma unroll
    for (int i = 0; i < 16; ++i) {
      float v = tile[s][cg * 16 + i];
      acc = fmaf(v, v, acc);
    }
    red[s][cg] = acc;
  }
  __syncthreads();
  if (t < 16) {
    float tot = 0.f;
#pragma unroll
    for (int g = 0; g < 16; ++g) tot += red[t][g];
    sinv[t] = scale_extra / fmaxf(sqrtf(tot), 1e-12f);  // eps = 1e-12
  }
  __syncthreads();

  // ---- write normalized f16: thread t -> row (t&15), 16-ch chunk (t>>4) ---
  {
    const int s = t & 15, c16 = t >> 4;
    const float inv = sinv[s];
    h8 o0, o1;
#pragma unroll
    for (int j = 0; j < 8; ++j) o0[j] = (_Float16)(tile[s][c16 * 16 + j] * inv);
#pragma unroll
    for (int j = 0; j < 8; ++j)
      o1[j] = (_Float16)(tile[s][c16 * 16 + 8 + j] * inv);
    h8* dst = (h8*)(out + (size_t)(n0 + s) * C_DIM + c16 * 16);
    dst[0] = o0;
    dst[1] = o1;
  }
}

// ---------------------------------------------------------------------------
// Kernel 2: per-row InfoNCE. One block per row, 32 units of 8 lanes.
// All rows pre-normalized (q rows carry 1/T) -> dots ARE logits; the only
// gather is kd (contiguous 128B per 8-lane unit per instr, no line
// amplification). Plain store of per-row loss.
// ---------------------------------------------------------------------------
__global__ __launch_bounds__(256) void nce_kernel(
    const _Float16* __restrict__ qh, const _Float16* __restrict__ kh,
    const int* __restrict__ neg, float* __restrict__ loss_buf) {
  const int n = blockIdx.x;
  const int t = threadIdx.x;
  const int lane = t & 63;
  const int w = t >> 6;
  const int sub = lane & 7;              // lane within 8-lane dot unit
  const int unit = w * 8 + (lane >> 3);  // 0..31

  __shared__ float sneg[K_NEG];
  __shared__ float s_lpos;

  // ---- indices ----
  int r[4];
#pragma unroll
  for (int j = 0; j < 4; ++j) {
    int x = neg[(size_t)n * K_NEG + j * 32 + unit];
    r[j] = x + (x >= n ? 1 : 0);         // self-exclusion shift
  }
  // ---- q chunks: lane sub owns h8 chunks {sub, 8+sub, 16+sub, 24+sub} ----
  const h8* qrow = (const h8*)(qh + (size_t)n * C_DIM);
  h8 qv[4];
#pragma unroll
  for (int i = 0; i < 4; ++i) qv[i] = qrow[i * 8 + sub];
  // ---- positive row (unit 0 only) ----
  h8 kp[4];
  if (unit == 0) {
    const h8* kr = (const h8*)(kh + (size_t)n * C_DIM);
#pragma unroll
    for (int i = 0; i < 4; ++i) kp[i] = kr[i * 8 + sub];
  }
  // ---- 16 gathered k chunks ----
  h8 kd[4][4];
#pragma unroll
  for (int j = 0; j < 4; ++j) {
    const h8* kr = (const h8*)(kh + (size_t)r[j] * C_DIM);
#pragma unroll
    for (int i = 0; i < 4; ++i) kd[j][i] = kr[i * 8 + sub];
  }
  __builtin_amdgcn_sched_barrier(0);

  union H { h8 v; h2 p[4]; };

  // ---- 4 negative logits per unit ----
#pragma unroll
  for (int j = 0; j < 4; ++j) {
    float a0 = 0.f, a1 = 0.f;
#pragma unroll
    for (int i = 0; i < 4; ++i) {
      H a; a.v = qv[i];
      H b; b.v = kd[j][i];
      a0 = __builtin_amdgcn_fdot2(b.p[0], a.p[0], a0, false);
      a1 = __builtin_amdgcn_fdot2(b.p[1], a.p[1], a1, false);
      a0 = __builtin_amdgcn_fdot2(b.p[2], a.p[2], a0, false);
      a1 = __builtin_amdgcn_fdot2(b.p[3], a.p[3], a1, false);
    }
    float acc = a0 + a1;
    acc += __shfl_xor(acc, 1);
    acc += __shfl_xor(acc, 2);
    acc += __shfl_xor(acc, 4);
    if (sub == 0) sneg[j * 32 + unit] = acc;
  }
  // ---- positive logit ----
  if (unit == 0) {
    float a0 = 0.f, a1 = 0.f;
#pragma unroll
    for (int i = 0; i < 4; ++i) {
      H a; a.v = qv[i];
      H b; b.v = kp[i];
      a0 = __builtin_amdgcn_fdot2(b.p[0], a.p[0], a0, false);
      a1 = __builtin_amdgcn_fdot2(b.p[1], a.p[1], a1, false);
      a0 = __builtin_amdgcn_fdot2(b.p[2], a.p[2], a0, false);
      a1 = __builtin_amdgcn_fdot2(b.p[3], a.p[3], a1, false);
    }
    float acc = a0 + a1;
    acc += __shfl_xor(acc, 1);
    acc += __shfl_xor(acc, 2);
    acc += __shfl_xor(acc, 4);
    if (sub == 0) s_lpos = acc;
  }
  __syncthreads();

  // ---- wave 0: logsumexp over 129 logits (already scaled by 1/T) ----
  if (w == 0) {
    float lp = s_lpos;
    float x1 = sneg[lane];
    float x2 = sneg[lane + 64];
    float m = fmaxf(fmaxf(x1, x2), lp);
#pragma unroll
    for (int off = 32; off; off >>= 1) m = fmaxf(m, __shfl_xor(m, off));
    float s = __expf(x1 - m) + __expf(x2 - m);
#pragma unroll
    for (int off = 32; off; off >>= 1) s += __shfl_xor(s, off);
    if (lane == 0) loss_buf[n] = m + __logf(s) - lp;
  }
}

// ---------------------------------------------------------------------------
// Kernel 3: mean over 4096 per-row losses. One block, 1024 threads.
// ---------------------------------------------------------------------------
__global__ __launch_bounds__(1024) void reduce_kernel(
    const float* __restrict__ loss_buf, float* __restrict__ out) {
  const int t = threadIdx.x;
  const float4 v = ((const float4*)loss_buf)[t];
  float s = (v.x + v.y) + (v.z + v.w);
#pragma unroll
  for (int off = 32; off; off >>= 1) s += __shfl_xor(s, off);
  __shared__ float red[16];
  if ((t & 63) == 0) red[t >> 6] = s;
  __syncthreads();
  if (t < 16) {
    float x = red[t];
#pragma unroll
    for (int off = 8; off; off >>= 1) x += __shfl_xor(x, off);
    if (t == 0) out[0] = x * (1.0f / N_TOTAL);
  }
}

extern "C" void kernel_launch(void* const* d_in, const int* in_sizes, int n_in,
                              void* d_out, int out_size, void* d_ws,
                              size_t ws_size, hipStream_t stream) {
  const float* fq = (const float*)d_in[0];
  const float* fk = (const float*)d_in[1];
  const int* neg = (const int*)d_in[2];
  float* out = (float*)d_out;

  _Float16* qh = (_Float16*)d_ws;                        // 2 MiB
  _Float16* kh = qh + (size_t)N_TOTAL * C_DIM;           // 2 MiB
  float* loss_buf = (float*)(kh + (size_t)N_TOTAL * C_DIM);  // 16 KiB

  hipLaunchKernelGGL(norm_tr_kernel, dim3(512), dim3(256), 0, stream,
                     fq, fk, qh, kh);
  hipLaunchKernelGGL(nce_kernel, dim3(N_TOTAL), dim3(256), 0, stream,
                     qh, kh, neg, loss_buf);
  hipLaunchKernelGGL(reduce_kernel, dim3(1), dim3(1024), 0, stream,
                     loss_buf, out);
}